// Round 1
// baseline (76.211 us; speedup 1.0000x reference)
//
#include <hip/hip_runtime.h>
#include <stdint.h>

#define N_ 8192
#define D_ 64
#define B_ 2
#define M_ 3

typedef __attribute__((ext_vector_type(8))) short short8;
typedef __attribute__((ext_vector_type(8))) __bf16 bf16x8;
typedef __attribute__((ext_vector_type(4))) float f32x4;

// float -> bf16 (round-to-nearest-even) on raw bits
__device__ __forceinline__ short f2bf(float f) {
    uint32_t u = __builtin_bit_cast(uint32_t, f);
    u = (u + 0x7FFFu + ((u >> 16) & 1u)) >> 16;
    return (short)(u & 0xFFFFu);
}

__device__ __forceinline__ f32x4 mfma16(short8 a, short8 b, f32x4 c) {
    return __builtin_amdgcn_mfma_f32_16x16x32_bf16(
        __builtin_bit_cast(bf16x8, a), __builtin_bit_cast(bf16x8, b), c, 0, 0, 0);
}

// ============================================================================
// Kernel 1: diag/superdiag dot products, fully-coalesced Wf streaming.
//   d_m[j]   = X[j]   . Wf[m][:,j] + bf[m][j]
//   o_m[j-1] = X[j-1] . Wf[m][:,j] + bf[m][j]
// Both consume Wf column j -> lane l owns column j = c0+l; for each d the wave
// reads Wf[m][d][c0..c0+63] = one 256B coalesced segment. Wf read EXACTLY once
// chip-wide (vs ~4-6x effective in the fused kernel's 80B-granule gather).
// ============================================================================
#define K1COLS 64
#define K1SR   (K1COLS + 1)   // staged X rows c0-1 .. c0+63
#define K1PAD  68             // 16B-aligned rows for f32x4 staging

__global__ __launch_bounds__(256, 4) void dots_kernel(
    const float* __restrict__ X,     // [B][N][64]
    const float* __restrict__ Wf,    // [3][64][N]
    const float* __restrict__ bfv,   // [3][N]
    float* __restrict__ dd,          // [B*3][N]
    float* __restrict__ oo)          // [B*3][N]
{
    __shared__ __align__(16) float Xs[K1SR][K1PAD];
    const int tid = threadIdx.x;
    const int bid = blockIdx.x;
    const int b   = bid & 1;
    const int c0  = (bid >> 1) * K1COLS;
    const float* Xb = X + (size_t)b * N_ * D_;

    // stage X rows c0-1 .. c0+63 (coalesced f32x4)
    for (int p = tid; p < K1SR * 16; p += 256) {
        int rr = p >> 4, c4 = p & 15;
        int row = (c0 - 1 + rr + N_) & (N_ - 1);
        f32x4 v = *(const f32x4*)(Xb + (size_t)row * D_ + c4 * 4);
        *(f32x4*)&Xs[rr][c4 * 4] = v;
    }
    __syncthreads();

    const int w = tid >> 6;       // wave = m
    if (w >= M_) return;          // wave 3 helped stage; done
    const int l = tid & 63;
    const int j = c0 + l;         // this lane's Wf column
    const float* wp = Wf + (size_t)w * D_ * N_ + j;

    float ad = bfv[w * N_ + j];   // d[j]  gets +bf[m][j]
    float ao = ad;                // o[j-1] gets +bf[m][j] too
    #pragma unroll 4
    for (int dg = 0; dg < 16; ++dg) {
        float w0 = wp[(size_t)(dg * 4 + 0) * N_];
        float w1 = wp[(size_t)(dg * 4 + 1) * N_];
        float w2 = wp[(size_t)(dg * 4 + 2) * N_];
        float w3 = wp[(size_t)(dg * 4 + 3) * N_];
        f32x4 xa = *(const f32x4*)&Xs[l + 1][dg * 4];   // X row j
        f32x4 xb = *(const f32x4*)&Xs[l][dg * 4];       // X row j-1
        ad += xa[0] * w0 + xa[1] * w1 + xa[2] * w2 + xa[3] * w3;
        ao += xb[0] * w0 + xb[1] * w1 + xb[2] * w2 + xb[3] * w3;
    }
    const size_t obase = (size_t)(b * M_ + w) * N_;
    dd[obase + j] = ad;
    oo[obase + ((j - 1) & (N_ - 1))] = ao;
}

// ============================================================================
// Kernel 2: chain coefficients from dd/oo (12 tiny cached loads) + Y = sum_k
// c_k X[i+k], MFMA with Wg. Identical proven math/epilogue as before; the
// entire Wfs staging + 54-thread dot phase is gone (LDS 22KB -> 5.4KB).
// ============================================================================
#define ROWS 16
#define SR (ROWS + 4)
#define PAD 68

__global__ __launch_bounds__(256, 4) void smf_kernel(
    const float* __restrict__ X,    // [B][N][64]
    const float* __restrict__ Wg,   // [64][64]
    const float* __restrict__ bg,   // [64]
    const float* __restrict__ dd,   // [B*3][N]
    const float* __restrict__ oo,   // [B*3][N]
    float* __restrict__ Out)        // [B][N][64]
{
    __shared__ __align__(16) float Xs[SR][PAD];

    const int tid = threadIdx.x;
    const int bid = blockIdx.x;
    const int b   = bid & 1;
    const int r0  = (bid >> 1) * ROWS;
    const float* Xb = X + (size_t)b * N_ * D_;

    const int w  = tid >> 6;   // wave id = output col-tile
    const int l  = tid & 63;
    const int lo = l & 15;
    const int q  = l >> 4;

    // ---- coefficient loads (pure global, independent of LDS -> overlap) ----
    const int i0 = r0 + lo;
    const int i1 = (i0 + 1) & (N_ - 1);
    const int i2 = (i0 + 2) & (N_ - 1);
    const size_t base0 = (size_t)(b * M_ + 0) * N_;
    const size_t base1 = (size_t)(b * M_ + 1) * N_;
    const size_t base2 = (size_t)(b * M_ + 2) * N_;
    float D0  = dd[base0 + i0], D0p = dd[base0 + i1], D0q = dd[base0 + i2];
    float O0  = oo[base0 + i0], O0p = oo[base0 + i1], O0q = oo[base0 + i2];
    float D1  = dd[base1 + i0], D1p = dd[base1 + i1];
    float O1  = oo[base1 + i0], O1p = oo[base1 + i1];
    float D2  = dd[base2 + i0], O2  = oo[base2 + i0];

    // ---- stage X rows r0..r0+19 (coalesced f32x4) ----
    for (int p = tid; p < SR * 16; p += 256) {
        int rr = p >> 4, c4 = p & 15;
        int row = (r0 + rr) & (N_ - 1);
        f32x4 v = *(const f32x4*)(Xb + (size_t)row * D_ + c4 * 4);
        *(f32x4*)&Xs[rr][c4 * 4] = v;
    }

    // ---- B fragments (Wg) + bg ----
    short8 Bfrag[2];
    #pragma unroll
    for (int kh = 0; kh < 2; ++kh) {
        short8 s;
        #pragma unroll
        for (int jj = 0; jj < 8; ++jj) {
            int k = kh * 32 + q * 8 + jj;            // B[k][n], n = lane&15
            s[jj] = f2bf(Wg[k * 64 + w * 16 + lo]);
        }
        Bfrag[kh] = s;
    }
    const float bgv = bg[w * 16 + lo];

    __syncthreads();   // staging complete

    // ---- chain coefficients for row i0 ----
    float ck0 = D2 * D1 * D0;
    float ck1 = D2 * D1 * O0 + D2 * O1 * D0p + O2 * D1p * D0p;
    float ck2 = D2 * O1 * O0p + O2 * D1p * O0p + O2 * O1p * D0q;
    float ck3 = O2 * O1p * O0q;
    float csum = ck0 + ck1 + ck2 + ck3;
    float ck[4] = {ck0, ck1, ck2, ck3};

    // ---- Y = sum_k c_k * X[i+k] in A-frag layout -> MFMA ----
    f32x4 acc = (f32x4){0.f, 0.f, 0.f, 0.f};
    #pragma unroll
    for (int kh = 0; kh < 2; ++kh) {
        int cbase = kh * 32 + q * 8;
        f32x4 ya = (f32x4){0.f, 0.f, 0.f, 0.f};
        f32x4 yb = (f32x4){0.f, 0.f, 0.f, 0.f};
        #pragma unroll
        for (int k = 0; k < 4; ++k) {
            f32x4 xa = *(const f32x4*)&Xs[lo + k][cbase];
            f32x4 xb = *(const f32x4*)&Xs[lo + k][cbase + 4];
            #pragma unroll
            for (int t = 0; t < 4; ++t) { ya[t] += ck[k] * xa[t]; yb[t] += ck[k] * xb[t]; }
        }
        short8 A;
        #pragma unroll
        for (int jj = 0; jj < 4; ++jj) { A[jj] = f2bf(ya[jj]); A[4 + jj] = f2bf(yb[jj]); }
        acc = mfma16(A, Bfrag[kh], acc);
    }

    // ---- epilogue: C/D layout col=lane&15, row=q*4+r; csum via shuffle ----
    #pragma unroll
    for (int r = 0; r < 4; ++r) {
        int orow = q * 4 + r;
        float cs = __shfl(csum, orow);
        float v = acc[r] + cs * bgv;
        Out[((size_t)b * N_ + (r0 + orow)) * D_ + w * 16 + lo] = v;
    }
}

extern "C" void kernel_launch(void* const* d_in, const int* in_sizes, int n_in,
                              void* d_out, int out_size, void* d_ws, size_t ws_size,
                              hipStream_t stream) {
    const float* X   = (const float*)d_in[0];
    const float* Wg  = (const float*)d_in[1];
    const float* bg  = (const float*)d_in[2];
    const float* Wf  = (const float*)d_in[3];
    const float* bfv = (const float*)d_in[4];
    float* Out = (float*)d_out;

    float* dd = (float*)d_ws;                      // [B*3][N] = 196KB
    float* oo = dd + (size_t)B_ * M_ * N_;         // [B*3][N] = 196KB

    dim3 g1(2 * (N_ / K1COLS));   // 256 blocks, 1/CU
    hipLaunchKernelGGL(dots_kernel, g1, dim3(256), 0, stream, X, Wf, bfv, dd, oo);

    dim3 g2(2 * (N_ / ROWS));     // 1024 blocks, 4/CU
    hipLaunchKernelGGL(smf_kernel, g2, dim3(256), 0, stream, X, Wg, bg, dd, oo, Out);
}

// Round 2
// 70.731 us; speedup vs baseline: 1.0775x; 1.0775x over previous
//
#include <hip/hip_runtime.h>
#include <stdint.h>

#define N_ 8192
#define D_ 64
#define B_ 2
#define M_ 3
#define ROWS 64      // output rows per block
#define SRX 67       // staged X rows r0 .. r0+66
#define PAD 68       // LDS inner pad: stride%32==4 -> 2-way max (free), 16B aligned
#define NDOT 67      // dot columns jj = 0..66 (local)

typedef __attribute__((ext_vector_type(8))) short short8;
typedef __attribute__((ext_vector_type(8))) __bf16 bf16x8;
typedef __attribute__((ext_vector_type(4))) float f32x4;

// float -> bf16 (round-to-nearest-even) on raw bits
__device__ __forceinline__ short f2bf(float f) {
    uint32_t u = __builtin_bit_cast(uint32_t, f);
    u = (u + 0x7FFFu + ((u >> 16) & 1u)) >> 16;
    return (short)(u & 0xFFFFu);
}

__device__ __forceinline__ f32x4 mfma16(short8 a, short8 b, f32x4 c) {
    return __builtin_amdgcn_mfma_f32_16x16x32_bf16(
        __builtin_bit_cast(bf16x8, a), __builtin_bit_cast(bf16x8, b), c, 0, 0, 0);
}

// ============================================================================
// Single fused kernel. 256 blocks (b = bid>>7 so b=0/b=1 twins with the same
// r0 land on the same XCD under round-robin dispatch -> Wf L2 sharing),
// 512 threads, 64 output rows/block.
// Phase 1: stage X rows r0..r0+66 into LDS (coalesced f32x4) + Wg B-frags.
// Phase 2: 402 threads compute diag/superdiag dots block-locally; each
//          (m, col, d-half) thread does 32 fully-unrolled strided Wf loads
//          (per-wave the 67-col span is contiguous 268B -> coalesced lines).
// Phase 3: chain coefficients + Y = sum_k c_k X[i+k] -> MFMA (proven math).
// ============================================================================
__global__ __launch_bounds__(512, 2) void smf_fused(
    const float* __restrict__ X,    // [B][N][64]
    const float* __restrict__ Wg,   // [64][64]
    const float* __restrict__ bg,   // [64]
    const float* __restrict__ Wf,   // [3][64][N]
    const float* __restrict__ bfv,  // [3][N]
    float* __restrict__ Out)        // [B][N][64]
{
    __shared__ __align__(16) float Xs[SRX][PAD];     // 18.2 KB
    __shared__ float ddP[M_][NDOT + 1][2];           // d-dot halves
    __shared__ float ooP[M_][NDOT + 1][2];           // o-dot halves; idx jj holds o[jj-1]

    const int tid = threadIdx.x;
    const int bid = blockIdx.x;
    const int b   = bid >> 7;
    const int r0  = (bid & 127) * ROWS;
    const float* Xb = X + (size_t)b * N_ * D_;

    // ---- phase 1a: stage X rows r0..r0+66 (coalesced f32x4) ----
    for (int p = tid; p < SRX * 16; p += 512) {
        int rr = p >> 4, c4 = p & 15;
        int row = (r0 + rr) & (N_ - 1);
        f32x4 v = *(const f32x4*)(Xb + (size_t)row * D_ + c4 * 4);
        *(f32x4*)&Xs[rr][c4 * 4] = v;
    }

    // ---- phase 1b: Wg B-fragments + bg (pure global, overlaps staging) ----
    const int w  = tid >> 6;          // wave 0..7
    const int l  = tid & 63;
    const int lo = l & 15;
    const int q  = l >> 4;
    const int rt  = w >> 1;           // row-tile 0..3 (16 rows each)
    const int ct0 = (w & 1) * 2;      // first of two col-tiles

    short8 Bf[2][2];                  // [kh][ci]
    #pragma unroll
    for (int kh = 0; kh < 2; ++kh) {
        #pragma unroll
        for (int ci = 0; ci < 2; ++ci) {
            short8 s;
            #pragma unroll
            for (int jj = 0; jj < 8; ++jj) {
                int k = kh * 32 + q * 8 + jj;       // B[k][n], n = lane&15
                s[jj] = f2bf(Wg[k * 64 + (ct0 + ci) * 16 + lo]);
            }
            Bf[kh][ci] = s;
        }
    }
    const float bgv0 = bg[(ct0 + 0) * 16 + lo];
    const float bgv1 = bg[(ct0 + 1) * 16 + lo];

    __syncthreads();   // X staged

    // ---- phase 2: dots. thread -> (m, jj, dh); 3*67*2 = 402 active ----
    if (tid < M_ * NDOT * 2) {
        int m  = tid / (NDOT * 2);
        int r  = tid - m * (NDOT * 2);
        int jj = r >> 1;              // local col 0..66
        int dh = r & 1;               // d half
        int j  = (r0 + jj) & (N_ - 1);
        const float* wp = Wf + ((size_t)(m * D_ + dh * 32)) * N_ + j;
        float bfval = bfv[m * N_ + j];
        float ad = dh ? 0.f : bfval;  // dd[jj]   = X[jj]  .col[jj] + bf[jj]
        float ao = dh ? 0.f : bfval;  // oo@jj    = X[jj-1].col[jj] + bf[jj]  (= o[jj-1])
        const int jb = jj ? jj - 1 : 0;   // jj==0 result unused
        #pragma unroll
        for (int dg = 0; dg < 8; ++dg) {
            float w0 = wp[(size_t)(dg * 4 + 0) * N_];
            float w1 = wp[(size_t)(dg * 4 + 1) * N_];
            float w2 = wp[(size_t)(dg * 4 + 2) * N_];
            float w3 = wp[(size_t)(dg * 4 + 3) * N_];
            f32x4 xa = *(const f32x4*)&Xs[jj][dh * 32 + dg * 4];
            f32x4 xb = *(const f32x4*)&Xs[jb][dh * 32 + dg * 4];
            ad += xa[0] * w0 + xa[1] * w1 + xa[2] * w2 + xa[3] * w3;
            ao += xb[0] * w0 + xb[1] * w1 + xb[2] * w2 + xb[3] * w3;
        }
        ddP[m][jj][dh] = ad;
        ooP[m][jj][dh] = ao;
    }
    __syncthreads();   // dots visible

    // ---- phase 3: chain coefficients for local row iL ----
    const int iL = rt * 16 + lo;
    #define DDv(m, i) (ddP[m][i][0] + ddP[m][i][1])
    #define OOv(m, i) (ooP[m][(i) + 1][0] + ooP[m][(i) + 1][1])
    float D0  = DDv(0, iL),     O0  = OOv(0, iL);
    float D0p = DDv(0, iL + 1), O0p = OOv(0, iL + 1);
    float D0q = DDv(0, iL + 2), O0q = OOv(0, iL + 2);
    float D1  = DDv(1, iL),     O1  = OOv(1, iL);
    float D1p = DDv(1, iL + 1), O1p = OOv(1, iL + 1);
    float D2  = DDv(2, iL),     O2  = OOv(2, iL);
    float ck0 = D2 * D1 * D0;
    float ck1 = D2 * D1 * O0 + D2 * O1 * D0p + O2 * D1p * D0p;
    float ck2 = D2 * O1 * O0p + O2 * D1p * O0p + O2 * O1p * D0q;
    float ck3 = O2 * O1p * O0q;
    float csum = ck0 + ck1 + ck2 + ck3;
    float ck[4] = {ck0, ck1, ck2, ck3};

    // ---- Y = sum_k c_k * X[iL+k] in A-frag layout -> 2 col-tiles of MFMA ----
    f32x4 acc0 = (f32x4){0.f, 0.f, 0.f, 0.f};
    f32x4 acc1 = (f32x4){0.f, 0.f, 0.f, 0.f};
    #pragma unroll
    for (int kh = 0; kh < 2; ++kh) {
        int cbase = kh * 32 + q * 8;
        f32x4 ya = (f32x4){0.f, 0.f, 0.f, 0.f};
        f32x4 yb = (f32x4){0.f, 0.f, 0.f, 0.f};
        #pragma unroll
        for (int k = 0; k < 4; ++k) {
            f32x4 xa = *(const f32x4*)&Xs[iL + k][cbase];
            f32x4 xb = *(const f32x4*)&Xs[iL + k][cbase + 4];
            #pragma unroll
            for (int t = 0; t < 4; ++t) { ya[t] += ck[k] * xa[t]; yb[t] += ck[k] * xb[t]; }
        }
        short8 A;
        #pragma unroll
        for (int jj = 0; jj < 4; ++jj) { A[jj] = f2bf(ya[jj]); A[4 + jj] = f2bf(yb[jj]); }
        acc0 = mfma16(A, Bf[kh][0], acc0);
        acc1 = mfma16(A, Bf[kh][1], acc1);
    }

    // ---- epilogue: C/D layout col=lane&15, row=q*4+r; csum via shuffle ----
    #pragma unroll
    for (int r = 0; r < 4; ++r) {
        int orow = q * 4 + r;
        float cs = __shfl(csum, orow);        // lane orow (q=0) holds row rt*16+orow
        size_t rowbase = ((size_t)b * N_ + (r0 + rt * 16 + orow)) * D_;
        Out[rowbase + (ct0 + 0) * 16 + lo] = acc0[r] + cs * bgv0;
        Out[rowbase + (ct0 + 1) * 16 + lo] = acc1[r] + cs * bgv1;
    }
}

extern "C" void kernel_launch(void* const* d_in, const int* in_sizes, int n_in,
                              void* d_out, int out_size, void* d_ws, size_t ws_size,
                              hipStream_t stream) {
    const float* X   = (const float*)d_in[0];
    const float* Wg  = (const float*)d_in[1];
    const float* bg  = (const float*)d_in[2];
    const float* Wf  = (const float*)d_in[3];
    const float* bfv = (const float*)d_in[4];
    float* Out = (float*)d_out;

    dim3 grid(B_ * (N_ / ROWS));   // 256 blocks, 1/CU, 8 waves/CU
    dim3 block(512);
    hipLaunchKernelGGL(smf_fused, grid, block, 0, stream, X, Wg, bg, Wf, bfv, Out);
}